// Round 12
// baseline (91.497 us; speedup 1.0000x reference)
//
#include <hip/hip_runtime.h>
#include <hip/hip_bf16.h>

// Problem constants (hardcoded in the reference)
#define B_SZ 512
#define D_SZ 1024
#define NK 160
#define NCOL 480          // NK*3
#define OUTW 1184         // D + NK
#define LOG2E 1.44269504088896340736f
#define GEMM_REPS 4       // amplification (measurement round): GEMM-internal time
#define PAIR_REPS 5       // amplification: pairwise compute time

typedef __attribute__((ext_vector_type(8))) short bf16x8;
typedef __attribute__((ext_vector_type(4))) float f32x4;

__device__ __forceinline__ unsigned int f32_bf16_rne(float f) {
    unsigned int u = __float_as_uint(f);
    u += 0x7fffu + ((u >> 16) & 1u);   // round-to-nearest-even at bf16 boundary
    return u >> 16;
}
__device__ __forceinline__ unsigned int pk2(float x, float y) {
    return f32_bf16_rne(x) | (f32_bf16_rne(y) << 16);
}
__device__ __forceinline__ float bf16u_to_f32(unsigned int h) {
    return __uint_as_float(h << 16);
}

// ---------------- Dispatch 1: r7 GEMM, body repeated GEMM_REPS times (idempotent;
// stores each rep keep it non-DCE-able — r11 validated the pattern).
__global__ __launch_bounds__(256) void mbd_gemm_kernel(
    const float* __restrict__ A,      // [512][1024]
    const float* __restrict__ W,      // [1024][480]
    const float* __restrict__ bias,   // [480]
    float* __restrict__ out,          // [512][1184]
    float* __restrict__ act_t)        // ws: [480][512] f32, pre-scaled by log2e
{
    __shared__ char lds[32768];       // 2 bufs x (A 8K + Bh 4K + Bl 4K)
    const int bid = blockIdx.x;
    const int t = threadIdx.x;

    {
        const float4 v = *reinterpret_cast<const float4*>(&A[bid * D_SZ + t * 4]);
        *reinterpret_cast<float4*>(&out[bid * OUTW + t * 4]) = v;
    }
    if (bid >= 480) return;

    const int g = bid >> 3;
    const int bm = (bid & 7) * 2 + (g & 1);   // 0..15
    const int bn = g >> 1;                    // 0..29
    const int i0 = bm * 32, c0 = bn * 16;
    const int w = __builtin_amdgcn_readfirstlane(t >> 6);  // 0..3 uniform
    const int l = t & 63, lhi = l >> 4, llo = l & 15;

    const int arow = t >> 3, aseg = t & 7;
    const int wcol = t & 15, wkb = t >> 4;
    const int aswz = (arow & 7) << 4;
    const int wswz = (wcol & 7) << 4;
    const float* __restrict__ aptr = A + (size_t)(i0 + arow) * D_SZ + aseg * 16;
    const float* __restrict__ wptr = W + (size_t)wkb * 8 * NCOL + (c0 + wcol);

    f32x4 acc;
    float4 ra[4];
    float rw[8];

    auto issue_loads = [&](int k0) {
#pragma unroll
        for (int s = 0; s < 4; ++s)
            ra[s] = *reinterpret_cast<const float4*>(aptr + k0 + s * 4);
#pragma unroll
        for (int j = 0; j < 8; ++j)
            rw[j] = wptr[(size_t)(k0 + j) * NCOL];
    };
    auto write_stage = [&](int buf) {
        char* base = lds + buf * 16384;
        uint4 p0, p1;
        p0.x = pk2(ra[0].x, ra[0].y); p0.y = pk2(ra[0].z, ra[0].w);
        p0.z = pk2(ra[1].x, ra[1].y); p0.w = pk2(ra[1].z, ra[1].w);
        p1.x = pk2(ra[2].x, ra[2].y); p1.y = pk2(ra[2].z, ra[2].w);
        p1.z = pk2(ra[3].x, ra[3].y); p1.w = pk2(ra[3].z, ra[3].w);
        char* arp = base + arow * 256;
        *reinterpret_cast<uint4*>(arp + ((aseg * 32) ^ aswz)) = p0;
        *reinterpret_cast<uint4*>(arp + ((aseg * 32 + 16) ^ aswz)) = p1;
        unsigned int h[8]; float lo[8];
#pragma unroll
        for (int j = 0; j < 8; ++j) {
            h[j] = f32_bf16_rne(rw[j]);
            lo[j] = rw[j] - bf16u_to_f32(h[j]);
        }
        uint4 ph, pl;
        ph.x = h[0] | (h[1] << 16); ph.y = h[2] | (h[3] << 16);
        ph.z = h[4] | (h[5] << 16); ph.w = h[6] | (h[7] << 16);
        pl.x = pk2(lo[0], lo[1]); pl.y = pk2(lo[2], lo[3]);
        pl.z = pk2(lo[4], lo[5]); pl.w = pk2(lo[6], lo[7]);
        const int wo = (wkb * 16) ^ wswz;
        *reinterpret_cast<uint4*>(base + 8192 + wcol * 256 + wo) = ph;
        *reinterpret_cast<uint4*>(base + 12288 + wcol * 256 + wo) = pl;
    };
    auto compute = [&](int buf) {
        const char* base = lds + buf * 16384;
        const char* bsrc = base + ((w >= 2) ? 12288 : 8192);
        const int wrow = (w & 1) * 16;
#pragma unroll
        for (int ks = 0; ks < 4; ++ks) {
            const int koff = (lhi * 16 + ks * 64) ^ ((llo & 7) << 4);
            const bf16x8 af = *reinterpret_cast<const bf16x8*>(base + (wrow + llo) * 256 + koff);
            const bf16x8 bf = *reinterpret_cast<const bf16x8*>(bsrc + llo * 256 + koff);
            acc = __builtin_amdgcn_mfma_f32_16x16x32_bf16(af, bf, acc, 0, 0, 0);
        }
    };

    for (int rep = 0; rep < GEMM_REPS; ++rep) {
        acc = f32x4{0.f, 0.f, 0.f, 0.f};
        issue_loads(0);
        write_stage(0);
        __syncthreads();
        for (int ch = 0; ch < 8; ++ch) {
            if (ch < 7) issue_loads((ch + 1) * 128);
            compute(ch & 1);
            if (ch < 7) {
                __syncthreads();
                write_stage((ch + 1) & 1);
                __syncthreads();
            }
        }
        __syncthreads();
        float4* comb = reinterpret_cast<float4*>(lds);
        if (w >= 2) comb[(w - 2) * 64 + l] = make_float4(acc[0], acc[1], acc[2], acc[3]);
        __syncthreads();
        if (w < 2) {
            const float4 lo4 = comb[w * 64 + l];
            const int col = c0 + llo;
            const float bs = bias[col];
            float4 o;
            o.x = (acc[0] + lo4.x + bs) * LOG2E;
            o.y = (acc[1] + lo4.y + bs) * LOG2E;
            o.z = (acc[2] + lo4.z + bs) * LOG2E;
            o.w = (acc[3] + lo4.w + bs) * LOG2E;
            *reinterpret_cast<float4*>(&act_t[(size_t)col * B_SZ + i0 + (w & 1) * 16 + lhi * 4]) = o;
        }
        __syncthreads();   // protect LDS reuse across reps
    }
}

// ---------------- Dispatch 2: r7 pairwise, compute repeated PAIR_REPS times.
// Reps are chained through an opaque runtime-zero (kz) so the compiler cannot
// hoist/CSE the loop (rule #17); kz==0 at runtime => final values exact.
__global__ __launch_bounds__(64) void mbd_pairwise_kernel(
    const float* __restrict__ act_t,   // [480][512] planes
    float* __restrict__ out)           // [512][1184]
{
    __shared__ float4 as4[B_SZ];
    const int bid = blockIdx.x;
    const int klin = (bid & 7) * 320 + (bid >> 3);   // XCD-bijective
    const int k = klin >> 4;           // 0..159
    const int c = klin & 15;           // 0..15 (32-row chunk)
    const int t = threadIdx.x;         // 0..63

    const float* __restrict__ p0 = act_t + (size_t)(3 * k + 0) * B_SZ;
    const float* __restrict__ p1 = act_t + (size_t)(3 * k + 1) * B_SZ;
    const float* __restrict__ p2 = act_t + (size_t)(3 * k + 2) * B_SZ;
#pragma unroll
    for (int s = 0; s < 8; ++s) {
        const int idx = t + s * 64;
        as4[idx] = make_float4(p0[idx], p1[idx], p2[idx], 0.f);
    }
    __syncthreads();

    const int jq = t >> 3;             // 0..7 j-slice
    const int rg = t & 7;              // 0..7 row group
    const int r0 = c * 32 + rg * 4;
    const float4 a0 = as4[r0 + 0];
    const float4 a1 = as4[r0 + 1];
    const float4 a2 = as4[r0 + 2];
    const float4 a3 = as4[r0 + 3];

    float kz;                          // opaque zero: compiler can't fold acc*kz
    asm volatile("v_mov_b32 %0, 0" : "=v"(kz));

    float acc0 = 0.f, acc1 = 0.f, acc2 = 0.f, acc3 = 0.f;
    for (int rep = 0; rep < PAIR_REPS; ++rep) {
        // serial dependency on previous rep (runtime value: exactly 0)
        acc0 = __builtin_fmaf(acc0, kz, 0.f);
        acc1 = __builtin_fmaf(acc1, kz, 0.f);
        acc2 = __builtin_fmaf(acc2, kz, 0.f);
        acc3 = __builtin_fmaf(acc3, kz, 0.f);
#pragma unroll 8
        for (int jj = 0; jj < 64; ++jj) {
            const float4 av = as4[jq + jj * 8];
            acc0 += __builtin_amdgcn_exp2f(-(fabsf(a0.x - av.x) + fabsf(a0.y - av.y) + fabsf(a0.z - av.z)));
            acc1 += __builtin_amdgcn_exp2f(-(fabsf(a1.x - av.x) + fabsf(a1.y - av.y) + fabsf(a1.z - av.z)));
            acc2 += __builtin_amdgcn_exp2f(-(fabsf(a2.x - av.x) + fabsf(a2.y - av.y) + fabsf(a2.z - av.z)));
            acc3 += __builtin_amdgcn_exp2f(-(fabsf(a3.x - av.x) + fabsf(a3.y - av.y) + fabsf(a3.z - av.z)));
        }
    }
#pragma unroll
    for (int m = 8; m <= 32; m <<= 1) {
        acc0 += __shfl_xor(acc0, m);
        acc1 += __shfl_xor(acc1, m);
        acc2 += __shfl_xor(acc2, m);
        acc3 += __shfl_xor(acc3, m);
    }
    if (t < 8) {
        out[(size_t)(r0 + 0) * OUTW + D_SZ + k] = acc0;
        out[(size_t)(r0 + 1) * OUTW + D_SZ + k] = acc1;
        out[(size_t)(r0 + 2) * OUTW + D_SZ + k] = acc2;
        out[(size_t)(r0 + 3) * OUTW + D_SZ + k] = acc3;
    }
}

extern "C" void kernel_launch(void* const* d_in, const int* in_sizes, int n_in,
                              void* d_out, int out_size, void* d_ws, size_t ws_size,
                              hipStream_t stream)
{
    const float* inputs = (const float*)d_in[0];   // [512,1024] f32
    const float* W      = (const float*)d_in[1];   // [1024,480] f32
    const float* bias   = (const float*)d_in[2];   // [480] f32
    float* out = (float*)d_out;                    // [512,1184] f32
    float* act_t = (float*)d_ws;                   // [480][512] f32 = 983,040 B

    mbd_gemm_kernel<<<512, 256, 0, stream>>>(inputs, W, bias, out, act_t);
    mbd_pairwise_kernel<<<NK * 16, 64, 0, stream>>>(act_t, out);
}

// Round 13
// 27.782 us; speedup vs baseline: 3.2934x; 3.2934x over previous
//
#include <hip/hip_runtime.h>
#include <hip/hip_bf16.h>

// Problem constants (hardcoded in the reference)
#define B_SZ 512
#define D_SZ 1024
#define NK 160
#define NCOL 480          // NK*3
#define OUTW 1184         // D + NK
#define LOG2E 1.44269504088896340736f
#define PLANE 245760      // 480*512 floats per K-half partial plane

typedef __attribute__((ext_vector_type(8))) short bf16x8;
typedef __attribute__((ext_vector_type(4))) float f32x4;

__device__ __forceinline__ unsigned int f32_bf16_rne(float f) {
    unsigned int u = __float_as_uint(f);
    u += 0x7fffu + ((u >> 16) & 1u);   // round-to-nearest-even at bf16 boundary
    return u >> 16;
}
__device__ __forceinline__ unsigned int pk2(float x, float y) {
    return f32_bf16_rne(x) | (f32_bf16_rne(y) << 16);
}

// ---------------- Dispatch 1: MFMA GEMM, 32x32 tile, K-split 2, W plain bf16
// (r10 datum: absmax 1.0 without Wlo residual). 480 blocks x 256 thr (1.9/CU).
// 4 chunks of K=128; ONE barrier per chunk; loads issued a full chunk ahead.
// Wave w: rows (w&1)*16, cols (w>>1)*16 — no combine, direct store.
// act2[ksp][col][i] = partial (A[i,:].W[:,col] (+bias if ksp==0)) * log2e.
__global__ __launch_bounds__(256) void mbd_gemm_kernel(
    const float* __restrict__ A,      // [512][1024]
    const float* __restrict__ W,      // [1024][480]
    const float* __restrict__ bias,   // [480]
    float* __restrict__ act2)         // ws: [2][480][512] f32
{
    __shared__ char lds[32768];       // 2 bufs x (A 32x256B = 8K + W 32x256B = 8K)
    const int bid = blockIdx.x;       // 0..479
    const int xcd = bid & 7, loc = bid >> 3;    // loc 0..59
    const int bm = xcd * 2 + (loc & 1);         // 0..15 (XCD-local A rows)
    const int ksp = (loc >> 1) & 1;             // K-half
    const int bn = loc >> 2;                    // 0..14
    const int i0 = bm * 32, c0 = bn * 32, kb0 = ksp * 512;
    const int t = threadIdx.x;
    const int w = __builtin_amdgcn_readfirstlane(t >> 6);  // 0..3 uniform
    const int l = t & 63, lhi = l >> 4, llo = l & 15;

    // staging roles: A: 32 rows x 8 segs of 16 f32 (64B runs, coalesced);
    // W: 32 cols x 8 k-groups of 16 k (lanes 0-31 = contiguous 128B line).
    const int arow = t >> 3, aseg = t & 7;
    const int wcol = t & 31, wkg = t >> 5;
    const int aswz = (arow & 7) << 4;
    const int wswz = (wcol & 7) << 4;
    const float* __restrict__ aptr = A + (size_t)(i0 + arow) * D_SZ + kb0 + aseg * 16;
    const float* __restrict__ wptr = W + (size_t)(kb0 + wkg * 16) * NCOL + c0 + wcol;

    float4 ra[4];
    float rw[16];
    f32x4 acc = {0.f, 0.f, 0.f, 0.f};

    auto issue_loads = [&](int k0) {
#pragma unroll
        for (int s = 0; s < 4; ++s)
            ra[s] = *reinterpret_cast<const float4*>(aptr + k0 + s * 4);
#pragma unroll
        for (int j = 0; j < 16; ++j)
            rw[j] = wptr[(size_t)(k0 + j) * NCOL];
    };
    auto write_stage = [&](int buf) {
        char* base = lds + buf * 16384;
        char* arp = base + arow * 256;
        uint4 p0, p1;
        p0.x = pk2(ra[0].x, ra[0].y); p0.y = pk2(ra[0].z, ra[0].w);
        p0.z = pk2(ra[1].x, ra[1].y); p0.w = pk2(ra[1].z, ra[1].w);
        p1.x = pk2(ra[2].x, ra[2].y); p1.y = pk2(ra[2].z, ra[2].w);
        p1.z = pk2(ra[3].x, ra[3].y); p1.w = pk2(ra[3].z, ra[3].w);
        *reinterpret_cast<uint4*>(arp + ((aseg * 32) ^ aswz)) = p0;
        *reinterpret_cast<uint4*>(arp + ((aseg * 32 + 16) ^ aswz)) = p1;
        char* wrp = base + 8192 + wcol * 256;
        uint4 q0, q1;
        q0.x = pk2(rw[0], rw[1]);   q0.y = pk2(rw[2], rw[3]);
        q0.z = pk2(rw[4], rw[5]);   q0.w = pk2(rw[6], rw[7]);
        q1.x = pk2(rw[8], rw[9]);   q1.y = pk2(rw[10], rw[11]);
        q1.z = pk2(rw[12], rw[13]); q1.w = pk2(rw[14], rw[15]);
        *reinterpret_cast<uint4*>(wrp + ((wkg * 32) ^ wswz)) = q0;
        *reinterpret_cast<uint4*>(wrp + ((wkg * 32 + 16) ^ wswz)) = q1;
    };
    auto compute = [&](int buf) {
        const char* base = lds + buf * 16384;
        const int r0 = (w & 1) * 16, cc = (w >> 1) * 16;
        const int lswz = (llo & 7) << 4;
#pragma unroll
        for (int ks = 0; ks < 4; ++ks) {
            const int koff = (lhi * 16 + ks * 64) ^ lswz;
            const bf16x8 af = *reinterpret_cast<const bf16x8*>(base + (r0 + llo) * 256 + koff);
            const bf16x8 bf = *reinterpret_cast<const bf16x8*>(base + 8192 + (cc + llo) * 256 + koff);
            acc = __builtin_amdgcn_mfma_f32_16x16x32_bf16(af, bf, acc, 0, 0, 0);
        }
    };

    issue_loads(0);
    write_stage(0);
    issue_loads(128);                 // next chunk in flight across the barrier
    __syncthreads();
    for (int ch = 0; ch < 4; ++ch) {
        compute(ch & 1);
        if (ch < 3) {
            write_stage((ch + 1) & 1);             // vmcnt covered by compute
            if (ch < 2) issue_loads((ch + 2) * 128);
            __syncthreads();                       // single barrier per chunk
        }
    }

    // epilogue: C/D layout col=lane&15, row=(lane>>4)*4+reg; direct store
    const int r0 = (w & 1) * 16, cc = (w >> 1) * 16;
    const int col = c0 + cc + llo;
    const float bs = ksp ? 0.f : bias[col];
    float4 o;
    o.x = (acc[0] + bs) * LOG2E;
    o.y = (acc[1] + bs) * LOG2E;
    o.z = (acc[2] + bs) * LOG2E;
    o.w = (acc[3] + bs) * LOG2E;
    *reinterpret_cast<float4*>(
        &act2[(size_t)ksp * PLANE + (size_t)col * B_SZ + i0 + r0 + lhi * 4]) = o;
}

// ---------------- Dispatch 2: pairwise, 8 rows/lane + input->out copy (bid<512).
// 1280 blocks x 64 thr. Lane: rg=t&7 -> rows c*64+rg*8+{0..7}; jq=t>>3 ->
// j in {jq, jq+8, ...}: 1 ds_read_b128 feeds 8 rows (LDS pipe halved vs r7,
// 2x per-wave ILP). Staging sums the two K-half planes. exp2 on pre-scaled acts.
__global__ __launch_bounds__(64) void mbd_pairwise_kernel(
    const float* __restrict__ A,       // [512][1024] (for the copy)
    const float* __restrict__ act2,    // [2][480][512]
    float* __restrict__ out)           // [512][1184]
{
    __shared__ float4 as4[B_SZ];
    const int bid = blockIdx.x;
    const int t = threadIdx.x;         // 0..63

    if (bid < 512) {                   // fused input copy: one row per block
#pragma unroll
        for (int s = 0; s < 4; ++s) {
            const int idx = t + s * 64;
            const float4 v = *reinterpret_cast<const float4*>(&A[bid * D_SZ + idx * 4]);
            *reinterpret_cast<float4*>(&out[bid * OUTW + idx * 4]) = v;
        }
    }

    const int klin = (bid & 7) * 160 + (bid >> 3);   // XCD-bijective (1280 = 8x160)
    const int k = klin >> 3;           // 0..159
    const int c = klin & 7;            // 0..7 (64-row chunk)

    const float* __restrict__ p0 = act2 + (size_t)(3 * k + 0) * B_SZ;
    const float* __restrict__ p1 = act2 + (size_t)(3 * k + 1) * B_SZ;
    const float* __restrict__ p2 = act2 + (size_t)(3 * k + 2) * B_SZ;
#pragma unroll
    for (int s = 0; s < 8; ++s) {
        const int idx = t + s * 64;
        as4[idx] = make_float4(p0[idx] + p0[idx + PLANE],
                               p1[idx] + p1[idx + PLANE],
                               p2[idx] + p2[idx + PLANE], 0.f);
    }
    __syncthreads();

    const int jq = t >> 3;             // 0..7 j-slice
    const int rg = t & 7;              // 0..7 row group
    const int r0 = c * 64 + rg * 8;
    float ax[8], ay[8], az[8];
#pragma unroll
    for (int i = 0; i < 8; ++i) {
        const float4 v = as4[r0 + i];
        ax[i] = v.x; ay[i] = v.y; az[i] = v.z;
    }
    float acc[8];
#pragma unroll
    for (int i = 0; i < 8; ++i) acc[i] = 0.f;

#pragma unroll 4
    for (int jj = 0; jj < 64; ++jj) {
        const float4 av = as4[jq + jj * 8];   // conflict-free (8 addrs x 16B = 32 banks)
#pragma unroll
        for (int i = 0; i < 8; ++i)
            acc[i] += __builtin_amdgcn_exp2f(
                -(fabsf(ax[i] - av.x) + fabsf(ay[i] - av.y) + fabsf(az[i] - av.z)));
    }
#pragma unroll
    for (int m = 8; m <= 32; m <<= 1) {
#pragma unroll
        for (int i = 0; i < 8; ++i) acc[i] += __shfl_xor(acc[i], m);
    }
    if (t < 8) {
#pragma unroll
        for (int i = 0; i < 8; ++i)
            out[(size_t)(r0 + i) * OUTW + D_SZ + k] = acc[i];
    }
}

extern "C" void kernel_launch(void* const* d_in, const int* in_sizes, int n_in,
                              void* d_out, int out_size, void* d_ws, size_t ws_size,
                              hipStream_t stream)
{
    const float* inputs = (const float*)d_in[0];   // [512,1024] f32
    const float* W      = (const float*)d_in[1];   // [1024,480] f32
    const float* bias   = (const float*)d_in[2];   // [480] f32
    float* out = (float*)d_out;                    // [512,1184] f32
    float* act2 = (float*)d_ws;                    // [2][480][512] f32 = 1,966,080 B

    mbd_gemm_kernel<<<480, 256, 0, stream>>>(inputs, W, bias, act2);
    mbd_pairwise_kernel<<<1280, 64, 0, stream>>>(inputs, act2, out);
}

// Round 14
// 23.641 us; speedup vs baseline: 3.8704x; 1.1752x over previous
//
#include <hip/hip_runtime.h>
#include <hip/hip_bf16.h>

// Problem constants (hardcoded in the reference)
#define B_SZ 512
#define D_SZ 1024
#define NK 160
#define NCOL 480          // NK*3
#define OUTW 1184         // D + NK
#define LOG2E 1.44269504088896340736f
#define PLANE 245760      // 480*512 floats per K-half partial plane

typedef __attribute__((ext_vector_type(8))) short bf16x8;
typedef __attribute__((ext_vector_type(4))) float f32x4;

__device__ __forceinline__ unsigned int f32_bf16_rne(float f) {
    unsigned int u = __float_as_uint(f);
    u += 0x7fffu + ((u >> 16) & 1u);   // round-to-nearest-even at bf16 boundary
    return u >> 16;
}
__device__ __forceinline__ unsigned int pk2(float x, float y) {
    return f32_bf16_rne(x) | (f32_bf16_rne(y) << 16);
}

// ---------------- Dispatch 1: single-shot MFMA GEMM (NO chunk loop).
// 480 blocks x 256 thr (2 blocks/CU). Block = 32(M) x 32(N) tile, K-half 512
// (ksp split across blocks, r13-verified). Stage ALL of A(32x512)+W(32x512)
// as bf16 into 64KB LDS in ONE load burst -> one latency exposure -> ONE
// barrier -> 16 MFMA/wave -> direct store. Layouts/swizzles identical to the
// r13-verified compute path (1024B rows, (ent&7)<<4 XOR).
__global__ __launch_bounds__(256, 2) void mbd_gemm_kernel(
    const float* __restrict__ A,      // [512][1024]
    const float* __restrict__ W,      // [1024][480]
    const float* __restrict__ bias,   // [480]
    float* __restrict__ act2)         // ws: [2][480][512] f32
{
    __shared__ char lds[65536];       // A [32 rows][1024B] @0 ; W [32 cols][1024B] @32768
    const int bid = blockIdx.x;       // 0..479
    const int xcd = bid & 7, loc = bid >> 3;    // loc 0..59
    const int bm = xcd * 2 + (loc & 1);         // 0..15 (XCD-local A rows)
    const int ksp = (loc >> 1) & 1;             // K-half
    const int bn = loc >> 2;                    // 0..14
    const int i0 = bm * 32, c0 = bn * 32, kb0 = ksp * 512;
    const int t = threadIdx.x;
    const int w = __builtin_amdgcn_readfirstlane(t >> 6);  // 0..3 uniform
    const int l = t & 63, lhi = l >> 4, llo = l & 15;

    // ---- A: thread (arow=t>>3, aseg=t&7) loads f32 k = aseg*4 + 32q (+j)
    // => per load instr, 8 lanes of a row cover 128B contiguous (full lines).
    const int arow = t >> 3, aseg = t & 7;
    const int aswz = (arow & 7) << 4;
    const float* __restrict__ aptr = A + (size_t)(i0 + arow) * D_SZ + kb0 + aseg * 4;
    // ---- W: thread (kp8=t>>3, cq=t&7) loads float4 of cols 4cq..4cq+3 at
    // k in {2kp8, 2kp8+1} + 64m => per instr, 8 lanes cover one 128B row run.
    const int kp8 = t >> 3, cq = t & 7;
    const float* __restrict__ wbase = W + (size_t)(kb0 + 2 * kp8) * NCOL + c0 + 4 * cq;

    float4 ra[16], rw0[8], rw1[8];
#pragma unroll
    for (int q = 0; q < 16; ++q)
        ra[q] = *reinterpret_cast<const float4*>(aptr + q * 32);
#pragma unroll
    for (int m = 0; m < 8; ++m) {
        rw0[m] = *reinterpret_cast<const float4*>(wbase + (size_t)(64 * m) * NCOL);
        rw1[m] = *reinterpret_cast<const float4*>(wbase + (size_t)(64 * m + 1) * NCOL);
    }

    // ---- LDS writes (compiler inserts per-load waits; loads trickle in)
    {
        char* arp = lds + arow * 1024;
#pragma unroll
        for (int q = 0; q < 16; ++q) {
            uint2 p;
            p.x = pk2(ra[q].x, ra[q].y);
            p.y = pk2(ra[q].z, ra[q].w);
            // f32 k = aseg*4 + 32q -> kbyte = aseg*8 + 64q  (8B-aligned; XOR bits 4-6)
            *reinterpret_cast<uint2*>(arp + ((aseg * 8 + 64 * q) ^ aswz)) = p;
        }
#pragma unroll
        for (int m = 0; m < 8; ++m) {
            const int p = kp8 + 32 * m;           // k-pair index -> kbyte = 4p
#pragma unroll
            for (int j = 0; j < 4; ++j) {
                const int col = 4 * cq + j;
                const float v0 = (&rw0[m].x)[j];
                const float v1 = (&rw1[m].x)[j];
                *reinterpret_cast<unsigned int*>(
                    lds + 32768 + col * 1024 + ((4 * p) ^ ((col & 7) << 4))) = pk2(v0, v1);
            }
        }
    }
    __syncthreads();                   // the ONLY barrier

    // ---- compute: wave w = rows (w&1)*16, cols (w>>1)*16; 16 MFMA over K=512
    f32x4 acc = {0.f, 0.f, 0.f, 0.f};
    const int r0 = (w & 1) * 16, cc = (w >> 1) * 16;
    const int lswz = (llo & 7) << 4;
#pragma unroll
    for (int m = 0; m < 16; ++m) {
        const int koff = (lhi * 16 + m * 64) ^ lswz;
        const bf16x8 af = *reinterpret_cast<const bf16x8*>(lds + (r0 + llo) * 1024 + koff);
        const bf16x8 bf = *reinterpret_cast<const bf16x8*>(lds + 32768 + (cc + llo) * 1024 + koff);
        acc = __builtin_amdgcn_mfma_f32_16x16x32_bf16(af, bf, acc, 0, 0, 0);
    }

    // ---- epilogue: C/D layout col=lane&15, row=(lane>>4)*4+reg; direct store
    const int col = c0 + cc + llo;
    const float bs = ksp ? 0.f : bias[col];
    float4 o;
    o.x = (acc[0] + bs) * LOG2E;
    o.y = (acc[1] + bs) * LOG2E;
    o.z = (acc[2] + bs) * LOG2E;
    o.w = (acc[3] + bs) * LOG2E;
    *reinterpret_cast<float4*>(
        &act2[(size_t)ksp * PLANE + (size_t)col * B_SZ + i0 + r0 + lhi * 4]) = o;
}

// ---------------- Dispatch 2: pairwise, 8 rows/lane AT 10 waves/CU.
// 640 blocks x 256 thr (2.5 blocks/CU). Block = (k, 128-row chunk c);
// wave w: rows c*128 + w*32 + rg*8 (rg=lane&3), jq=lane>>2 -> 16 j-slices
// of 32. One ds_read_b128 feeds 8 rows; 16 addrs/wave = 2-way bank (free).
// Staging (sums both K-half planes) amortized over 4 waves. Copy in bid<512.
__global__ __launch_bounds__(256) void mbd_pairwise_kernel(
    const float* __restrict__ A,       // [512][1024] (for the copy)
    const float* __restrict__ act2,    // [2][480][512]
    float* __restrict__ out)           // [512][1184]
{
    __shared__ float4 as4[B_SZ];
    const int bid = blockIdx.x;        // 0..639
    const int t = threadIdx.x;         // 0..255

    if (bid < 512) {                   // fused input copy: one row per block
        const float4 v = *reinterpret_cast<const float4*>(&A[bid * D_SZ + t * 4]);
        *reinterpret_cast<float4*>(&out[bid * OUTW + t * 4]) = v;
    }

    const int klin = (bid & 7) * 80 + (bid >> 3);   // XCD-bijective (640 = 8x80)
    const int k = klin >> 2;           // 0..159
    const int c = klin & 3;            // 0..3 (128-row chunk)

    const float* __restrict__ p0 = act2 + (size_t)(3 * k + 0) * B_SZ;
    const float* __restrict__ p1 = act2 + (size_t)(3 * k + 1) * B_SZ;
    const float* __restrict__ p2 = act2 + (size_t)(3 * k + 2) * B_SZ;
#pragma unroll
    for (int s = 0; s < 2; ++s) {
        const int idx = t + s * 256;
        as4[idx] = make_float4(p0[idx] + p0[idx + PLANE],
                               p1[idx] + p1[idx + PLANE],
                               p2[idx] + p2[idx + PLANE], 0.f);
    }
    __syncthreads();

    const int w = t >> 6, lane = t & 63;
    const int rg = lane & 3;           // 0..3 row group
    const int jq = lane >> 2;          // 0..15 j-slice
    const int r0 = c * 128 + w * 32 + rg * 8;

    float ax[8], ay[8], az[8], acc[8];
#pragma unroll
    for (int i = 0; i < 8; ++i) {
        const float4 v = as4[r0 + i];
        ax[i] = v.x; ay[i] = v.y; az[i] = v.z;
        acc[i] = 0.f;
    }

#pragma unroll 4
    for (int jj = 0; jj < 32; ++jj) {
        const float4 av = as4[jq + jj * 16];
#pragma unroll
        for (int i = 0; i < 8; ++i)
            acc[i] += __builtin_amdgcn_exp2f(
                -(fabsf(ax[i] - av.x) + fabsf(ay[i] - av.y) + fabsf(az[i] - av.z)));
    }
    // reduce the 16 j-slices (lane bits 2..5)
#pragma unroll
    for (int m = 4; m <= 32; m <<= 1) {
#pragma unroll
        for (int i = 0; i < 8; ++i) acc[i] += __shfl_xor(acc[i], m);
    }
    if (lane < 4) {                    // rg == lane, jq == 0
#pragma unroll
        for (int i = 0; i < 8; ++i)
            out[(size_t)(r0 + i) * OUTW + D_SZ + k] = acc[i];
    }
}

extern "C" void kernel_launch(void* const* d_in, const int* in_sizes, int n_in,
                              void* d_out, int out_size, void* d_ws, size_t ws_size,
                              hipStream_t stream)
{
    const float* inputs = (const float*)d_in[0];   // [512,1024] f32
    const float* W      = (const float*)d_in[1];   // [1024,480] f32
    const float* bias   = (const float*)d_in[2];   // [480] f32
    float* out = (float*)d_out;                    // [512,1184] f32
    float* act2 = (float*)d_ws;                    // [2][480][512] f32 = 1,966,080 B

    mbd_gemm_kernel<<<480, 256, 0, stream>>>(inputs, W, bias, act2);
    mbd_pairwise_kernel<<<640, 256, 0, stream>>>(inputs, act2, out);
}